// Round 14
// baseline (372.547 us; speedup 1.0000x reference)
//
#include <hip/hip_runtime.h>
#include <hip/hip_bf16.h>

#define N_EXPERTS 32
#define K_SEL 4
#define IN_C 1024
#define OUT_C 1024
#define BATCH 4096
#define NTOK (BATCH * K_SEL)   // 16384

#define BM 128
#define BN 128
#define BK 64
#define MAX_TILES (N_EXPERTS + NTOK / BM)   // 160 worst case

// workspace layout: xb (bf16) | ctrl ints | wt (bf16) | flags
#define XB_ELEMS (BATCH * IN_C)                      // 4,194,304
#define WT_ELEMS (N_EXPERTS * IN_C * OUT_C)          // 33,554,432
#define CTRL_OFF_BYTES ((size_t)XB_ELEMS * 2)
#define WT_OFF_BYTES (CTRL_OFF_BYTES + 131072)
#define FLAGS_OFF_BYTES (WT_OFF_BYTES + (size_t)WT_ELEMS * 2)
#define N_CHUNKS (N_EXPERTS * 8 * 16)                // 4096

#define WS_NTILES 0
#define WS_TABLE 8                          // 4 ints per tile
#define WS_ROWLIST (WS_TABLE + MAX_TILES * 4)
#define CTRL_INTS (WS_ROWLIST + NTOK)
// fallback layout additions
#define WS_COUNTS (CTRL_INTS)
#define WS_CURSOR (CTRL_INTS + 32)

typedef __attribute__((ext_vector_type(4))) float f32x4;
typedef __attribute__((ext_vector_type(8))) short bf16x8;
typedef __attribute__((ext_vector_type(8))) unsigned short u16x8;
typedef __attribute__((ext_vector_type(4))) unsigned short u16x4;

__device__ __forceinline__ unsigned short f2bf(float f) {
    union { float f; unsigned u; } v; v.f = f;
    unsigned r = v.u + 0x7fffu + ((v.u >> 16) & 1u);   // RNE
    return (unsigned short)(r >> 16);
}

__device__ __forceinline__ void gload16(const void* g, void* l) {
    __builtin_amdgcn_global_load_lds(
        (const __attribute__((address_space(1))) unsigned int*)g,
        (__attribute__((address_space(3))) unsigned int*)l, 16, 0, 0);
}

// ---------------- prep: bucket (bid 0) + xconv ----------------

#define XCONV_B0 1
#define XCONV_NB (XB_ELEMS / 2048)          // 2048
#define PREP_NWG (XCONV_B0 + XCONV_NB)      // 2049

__global__ __launch_bounds__(256)
void prep_kernel(const float* __restrict__ x, const int* __restrict__ idx,
                 unsigned short* __restrict__ xb, int* __restrict__ ctrl) {
    const int bid = blockIdx.x;
    const int t = threadIdx.x;

    if (bid >= XCONV_B0) {
        int i = ((bid - XCONV_B0) * 256 + t) << 3;
        f32x4 v0 = *(const f32x4*)(x + i);
        f32x4 v1 = *(const f32x4*)(x + i + 4);
        u16x8 o;
        o[0] = f2bf(v0[0]); o[1] = f2bf(v0[1]); o[2] = f2bf(v0[2]); o[3] = f2bf(v0[3]);
        o[4] = f2bf(v1[0]); o[5] = f2bf(v1[1]); o[6] = f2bf(v1[2]); o[7] = f2bf(v1[3]);
        *(u16x8*)(xb + i) = o;
    } else {
        __shared__ int cnt[N_EXPERTS], base[N_EXPERTS], tbase[N_EXPERTS];
        if (t < N_EXPERTS) cnt[t] = 0;
        __syncthreads();
        #pragma unroll 4
        for (int i = 0; i < NTOK / 256; ++i) {
            int e = idx[i * 256 + t] & (N_EXPERTS - 1);
            atomicAdd(&cnt[e], 1);
        }
        __syncthreads();
        if (t == 0) {
            int off = 0, tiles = 0;
            for (int e = 0; e < N_EXPERTS; ++e) {
                base[e] = off;
                tbase[e] = tiles;
                int c = cnt[e];
                tiles += (c + BM - 1) / BM;
                off += c;
            }
            ctrl[WS_NTILES] = tiles;
        }
        __syncthreads();
        if (t < N_EXPERTS) {
            int c = cnt[t], off = base[t], tt = tbase[t];
            for (int u = 0; u < c; u += BM, ++tt) {
                ctrl[WS_TABLE + tt * 4 + 0] = t;
                ctrl[WS_TABLE + tt * 4 + 1] = off + u;
                ctrl[WS_TABLE + tt * 4 + 2] = (c - u) < BM ? (c - u) : BM;
            }
            cnt[t] = off;   // becomes scatter cursor
        }
        __syncthreads();
        #pragma unroll 4
        for (int i = 0; i < NTOK / 256; ++i) {
            int s = i * 256 + t;
            int e = idx[s] & (N_EXPERTS - 1);
            int p = atomicAdd(&cnt[e], 1);
            ctrl[WS_ROWLIST + p] = s;
        }
    }
}

// -------- R8 gemm + distributed dedup'd W->bf16 conversion (claim/done flags) --------
// Chunk (e, nb, ks) = rows ks*64..+64, cols nb*128..+128 of expert e's panel.
// Each block claims its 16 chunks; first claimer converts f32->bf16 into wt and
// release-stores done[]; all sharers wait (relaxed spin + one acquire fence), then
// run the proven R8 K-loop reading bf16 wt (L2-resident panels).

__global__ __launch_bounds__(256, 3)
void gemm_kernel(const unsigned short* __restrict__ xb,
                 const float* __restrict__ w,
                 unsigned short* __restrict__ wt,
                 const float* __restrict__ bias,
                 const int* __restrict__ ctrl,
                 int* claim, int* done,
                 float* __restrict__ out) {
    // expert-clustered XCD swizzle (proven): tile-major, nb-fastest
    const int swz = ((int)blockIdx.x & 7) * ((MAX_TILES * 8) >> 3) + ((int)blockIdx.x >> 3);
    const int tileIdx = swz >> 3;
    const int ntiles = ctrl[WS_NTILES];
    if (tileIdx >= ntiles) return;
    const int e     = ctrl[WS_TABLE + tileIdx * 4 + 0];
    const int list0 = ctrl[WS_TABLE + tileIdx * 4 + 1];
    const int nrows = ctrl[WS_TABLE + tileIdx * 4 + 2];
    const int nb = swz & 7;
    const int n0 = nb * BN;

    __shared__ unsigned short As[BM][BK];
    __shared__ unsigned short Bs[BN][BK];
    __shared__ int rowtok[BM];
    __shared__ int got;

    const int t = threadIdx.x;
    const int lane = t & 63, wv = t >> 6;

    if (t < BM) {
        int r = t < nrows ? t : nrows - 1;
        rowtok[t] = ctrl[WS_ROWLIST + list0 + r];
    }

    // ---- conversion preamble: claim & convert, then wait for panel ----
    const int cbase = (e * 8 + nb) * 16;
    const float* psrc = w + ((size_t)e << 20) + n0;
    unsigned short* pdst = wt + ((size_t)e << 20) + n0;
    for (int c = 0; c < 16; ++c) {
        __syncthreads();
        if (t == 0) got = (atomicCAS(&claim[cbase + c], 0, 1) == 0);
        __syncthreads();
        if (got) {
            const size_t rowoff = (size_t)(c << 6) << 10;
            #pragma unroll
            for (int u = 0; u < 4; ++u) {
                int un = (u << 8) + t;               // 1024 units: (row, 8-col group)
                int r = un >> 4, cg = (un & 15) << 3;
                f32x4 v0 = *(const f32x4*)(psrc + rowoff + ((size_t)r << 10) + cg);
                f32x4 v1 = *(const f32x4*)(psrc + rowoff + ((size_t)r << 10) + cg + 4);
                u16x8 ov;
                ov[0] = f2bf(v0[0]); ov[1] = f2bf(v0[1]); ov[2] = f2bf(v0[2]); ov[3] = f2bf(v0[3]);
                ov[4] = f2bf(v1[0]); ov[5] = f2bf(v1[1]); ov[6] = f2bf(v1[2]); ov[7] = f2bf(v1[3]);
                *(u16x8*)(pdst + rowoff + ((size_t)r << 10) + cg) = ov;
            }
            __syncthreads();   // all waves' stores drained (vmcnt0) before release
            if (t == 0)
                __hip_atomic_store(&done[cbase + c], 1, __ATOMIC_RELEASE, __HIP_MEMORY_SCOPE_AGENT);
        }
    }
    if (t == 0) {
        #pragma unroll 1
        for (int c = 0; c < 16; ++c)
            while (__hip_atomic_load(&done[cbase + c], __ATOMIC_RELAXED, __HIP_MEMORY_SCOPE_AGENT) == 0)
                __builtin_amdgcn_s_sleep(2);
        __builtin_amdgcn_fence(__ATOMIC_ACQUIRE, "agent");   // invalidate stale L2 lines
    }
    __syncthreads();

    // ---- proven R8 K-loop (byte-identical reads of wt) ----
    const int cg2 = (lane & 7) ^ (lane >> 3);
    const unsigned short* asrc[4];
    #pragma unroll
    for (int i = 0; i < 4; ++i) {
        int row = (wv << 5) + (i << 3) + (lane >> 3);
        asrc[i] = xb + (size_t)(rowtok[row] >> 2) * IN_C + (cg2 << 3);
    }
    const int q = t & 31, o = t >> 5;
    const unsigned short* bbase = wt + ((size_t)e << 20) + ((size_t)(o << 3) << 10) + n0 + (q << 2);

    const int wr = (t >> 7) & 1;
    const int wc = (t >> 6) & 1;
    const int lrow = lane & 15, lq = lane >> 4;
    const int afo0 = ((lq) ^ (lrow & 7)) << 4;
    const int afo1 = ((4 + lq) ^ (lrow & 7)) << 4;
    const char* aB = (const char*)&As[wr * 64 + lrow][0];
    const char* bB = (const char*)&Bs[wc * 64 + lrow][0];
    int bfo[2][4];
    #pragma unroll
    for (int kk = 0; kk < 2; ++kk)
        #pragma unroll
        for (int nf = 0; nf < 4; ++nf)
            bfo[kk][nf] = ((((kk << 2) + lq) ^ (lrow & 7) ^ ((2 * nf + (lrow >> 3)) & 7)) << 4);

    f32x4 acc[4][4];
    #pragma unroll
    for (int m = 0; m < 4; ++m)
        #pragma unroll
        for (int n = 0; n < 4; ++n) acc[m][n] = (f32x4)0.f;

    u16x4 breg[8];
    #pragma unroll
    for (int r = 0; r < 8; ++r)
        breg[r] = *(const u16x4*)(bbase + ((size_t)r << 10));

    for (int k0 = 0; k0 < IN_C; k0 += BK) {
        asm volatile("s_waitcnt lgkmcnt(0)" ::: "memory");
        __builtin_amdgcn_s_barrier();
        #pragma unroll
        for (int i = 0; i < 4; ++i)
            gload16(asrc[i] + k0, &As[(wv << 5) + (i << 3)][0]);
        __builtin_amdgcn_sched_barrier(0);
        #pragma unroll
        for (int j = 0; j < 4; ++j) {
            const int n = (q << 2) + j;
            const int phys = o ^ (n & 7) ^ ((n >> 3) & 7);
            u16x8 ov;
            #pragma unroll
            for (int r = 0; r < 8; ++r) ov[r] = breg[r][j];
            *(u16x8*)&Bs[n][phys << 3] = ov;
        }
        __builtin_amdgcn_sched_barrier(0);
        if (k0 + BK < IN_C) {
            const unsigned short* bs2 = bbase + ((size_t)(k0 + BK) << 10);
            #pragma unroll
            for (int r = 0; r < 8; ++r)
                breg[r] = *(const u16x4*)(bs2 + ((size_t)r << 10));
            __builtin_amdgcn_sched_barrier(0);
            asm volatile("s_waitcnt vmcnt(8)" ::: "memory");
        } else {
            asm volatile("s_waitcnt vmcnt(0)" ::: "memory");
        }
        asm volatile("s_waitcnt lgkmcnt(0)" ::: "memory");
        __builtin_amdgcn_sched_barrier(0);
        __builtin_amdgcn_s_barrier();
        #pragma unroll
        for (int kk = 0; kk < 2; ++kk) {
            const int afo = kk ? afo1 : afo0;
            bf16x8 a[4], b[4];
            #pragma unroll
            for (int m = 0; m < 4; ++m) a[m] = *(const bf16x8*)(aB + m * 2048 + afo);
            #pragma unroll
            for (int n = 0; n < 4; ++n) b[n] = *(const bf16x8*)(bB + n * 2048 + bfo[kk][n]);
            #pragma unroll
            for (int m = 0; m < 4; ++m)
                #pragma unroll
                for (int n = 0; n < 4; ++n)
                    acc[m][n] = __builtin_amdgcn_mfma_f32_16x16x32_bf16(a[m], b[n], acc[m][n], 0, 0, 0);
        }
    }

    // C/D layout: col = lane&15, row = (lane>>4)*4 + j   [verified m89/m91]
    #pragma unroll
    for (int m = 0; m < 4; ++m) {
        #pragma unroll
        for (int j = 0; j < 4; ++j) {
            int row = wr * 64 + m * 16 + lq * 4 + j;
            if (row < nrows) {
                int s = rowtok[row];
                float* orow = out + (size_t)s * OUT_C;
                #pragma unroll
                for (int n = 0; n < 4; ++n) {
                    int col = n0 + wc * 64 + n * 16 + lrow;
                    float vv = acc[m][n][j] + bias[e * OUT_C + col];
                    orow[col] = vv > 0.f ? vv : 0.f;
                }
            }
        }
    }
}

// ---------------- fallback f32 path (round-1 proven) for small ws ----------------

__global__ void count_kernel(const int* __restrict__ idx, int* __restrict__ ctrl) {
    int s = blockIdx.x * blockDim.x + threadIdx.x;
    if (s < NTOK) atomicAdd(&ctrl[WS_COUNTS + (idx[s] & (N_EXPERTS - 1))], 1);
}

__global__ void scan_kernel(int* __restrict__ ctrl) {
    if (threadIdx.x != 0) return;
    int off = 0, tiles = 0;
    for (int e = 0; e < N_EXPERTS; ++e) {
        int c = ctrl[WS_COUNTS + e];
        ctrl[WS_CURSOR + e] = off;
        for (int t = 0; t < c; t += BM) {
            ctrl[WS_TABLE + tiles * 4 + 0] = e;
            ctrl[WS_TABLE + tiles * 4 + 1] = off + t;
            ctrl[WS_TABLE + tiles * 4 + 2] = (c - t) < BM ? (c - t) : BM;
            ++tiles;
        }
        off += c;
    }
    ctrl[WS_NTILES] = tiles;
}

__global__ void scatter_kernel(const int* __restrict__ idx, int* __restrict__ ctrl) {
    int s = blockIdx.x * blockDim.x + threadIdx.x;
    if (s < NTOK) {
        int e = idx[s] & (N_EXPERTS - 1);
        int p = atomicAdd(&ctrl[WS_CURSOR + e], 1);
        ctrl[WS_ROWLIST + p] = s;
    }
}

__global__ __launch_bounds__(256, 2)
void gemm_f32_kernel(const float* __restrict__ x, const float* __restrict__ w,
                     const float* __restrict__ bias, const int* __restrict__ ctrl,
                     float* __restrict__ out) {
    int ntiles = ctrl[WS_NTILES];
    if ((int)blockIdx.x >= ntiles) return;
    const int e     = ctrl[WS_TABLE + blockIdx.x * 4 + 0];
    const int list0 = ctrl[WS_TABLE + blockIdx.x * 4 + 1];
    const int nrows = ctrl[WS_TABLE + blockIdx.x * 4 + 2];
    const int n0 = blockIdx.y * BN;

    __shared__ unsigned short As2[BM][40];
    __shared__ unsigned short Bs2[BN][40];
    __shared__ int rowtok[BM];

    const int t = threadIdx.x;
    if (t < BM) {
        int r = t < nrows ? t : nrows - 1;
        rowtok[t] = ctrl[WS_ROWLIST + list0 + r];
    }
    __syncthreads();

    const int arow = t >> 1, acol0 = (t & 1) * 16;
    const int brow = t >> 3, bcol0 = (t & 7) * 16;
    const float* xbase = x + (size_t)(rowtok[arow] >> 2) * IN_C + acol0;
    const float* wbase = w + (size_t)e * IN_C * OUT_C + (size_t)brow * OUT_C + n0 + bcol0;

    const int lane = t & 63, wid = t >> 6;
    const int wr = wid >> 1, wc = wid & 1;
    const int lrow = lane & 15, lq = lane >> 4;

    f32x4 acc[4][4];
    #pragma unroll
    for (int m = 0; m < 4; ++m)
        #pragma unroll
        for (int n = 0; n < 4; ++n) acc[m][n] = (f32x4)0.f;

    for (int k0 = 0; k0 < IN_C; k0 += 32) {
        __syncthreads();
        #pragma unroll
        for (int u = 0; u < 4; ++u) {
            f32x4 v = *(const f32x4*)(xbase + k0 + 4 * u);
            ushort4 pk;
            pk.x = f2bf(v[0]); pk.y = f2bf(v[1]); pk.z = f2bf(v[2]); pk.w = f2bf(v[3]);
            *(ushort4*)&As2[arow][acol0 + 4 * u] = pk;
        }
        #pragma unroll
        for (int u = 0; u < 4; ++u) {
            f32x4 v = *(const f32x4*)(wbase + (size_t)k0 * OUT_C + 4 * u);
            Bs2[bcol0 + 4 * u + 0][brow] = f2bf(v[0]);
            Bs2[bcol0 + 4 * u + 1][brow] = f2bf(v[1]);
            Bs2[bcol0 + 4 * u + 2][brow] = f2bf(v[2]);
            Bs2[bcol0 + 4 * u + 3][brow] = f2bf(v[3]);
        }
        __syncthreads();

        bf16x8 a[4], b[4];
        #pragma unroll
        for (int m = 0; m < 4; ++m) a[m] = *(const bf16x8*)&As2[wr * 64 + m * 16 + lrow][lq * 8];
        #pragma unroll
        for (int n = 0; n < 4; ++n) b[n] = *(const bf16x8*)&Bs2[wc * 64 + n * 16 + lrow][lq * 8];
        #pragma unroll
        for (int m = 0; m < 4; ++m)
            #pragma unroll
            for (int n = 0; n < 4; ++n)
                acc[m][n] = __builtin_amdgcn_mfma_f32_16x16x32_bf16(a[m], b[n], acc[m][n], 0, 0, 0);
    }

    #pragma unroll
    for (int m = 0; m < 4; ++m) {
        #pragma unroll
        for (int j = 0; j < 4; ++j) {
            int row = wr * 64 + m * 16 + lq * 4 + j;
            if (row < nrows) {
                int s = rowtok[row];
                float* orow = out + (size_t)s * OUT_C;
                #pragma unroll
                for (int n = 0; n < 4; ++n) {
                    int col = n0 + wc * 64 + n * 16 + lrow;
                    float vv = acc[m][n][j] + bias[e * OUT_C + col];
                    orow[col] = vv > 0.f ? vv : 0.f;
                }
            }
        }
    }
}

// ---------------- launch ----------------

extern "C" void kernel_launch(void* const* d_in, const int* in_sizes, int n_in,
                              void* d_out, int out_size, void* d_ws, size_t ws_size,
                              hipStream_t stream) {
    const float* x    = (const float*)d_in[0];
    const int*   idx  = (const int*)d_in[1];
    const float* w    = (const float*)d_in[2];
    const float* bias = (const float*)d_in[3];
    float* out = (float*)d_out;

    const size_t need = FLAGS_OFF_BYTES + (size_t)N_CHUNKS * 2 * sizeof(int);
    if (ws_size >= need) {
        unsigned short* xb = (unsigned short*)d_ws;
        int* ctrl = (int*)((char*)d_ws + CTRL_OFF_BYTES);
        unsigned short* wt = (unsigned short*)((char*)d_ws + WT_OFF_BYTES);
        int* claim = (int*)((char*)d_ws + FLAGS_OFF_BYTES);
        int* done = claim + N_CHUNKS;

        hipMemsetAsync(claim, 0, (size_t)N_CHUNKS * 2 * sizeof(int), stream);
        prep_kernel<<<PREP_NWG, 256, 0, stream>>>(x, idx, xb, ctrl);
        gemm_kernel<<<MAX_TILES * 8, 256, 0, stream>>>(xb, w, wt, bias, ctrl, claim, done, out);
    } else {
        int* ctrl = (int*)d_ws;
        hipMemsetAsync(ctrl, 0, (CTRL_INTS + 64) * sizeof(int), stream);
        count_kernel<<<NTOK / 256, 256, 0, stream>>>(idx, ctrl);
        scan_kernel<<<1, 64, 0, stream>>>(ctrl);
        scatter_kernel<<<NTOK / 256, 256, 0, stream>>>(idx, ctrl);
        dim3 grid(MAX_TILES, OUT_C / BN);
        gemm_f32_kernel<<<grid, 256, 0, stream>>>(x, w, bias, ctrl, out);
    }
}

// Round 15
// 345.295 us; speedup vs baseline: 1.0789x; 1.0789x over previous
//
#include <hip/hip_runtime.h>
#include <hip/hip_bf16.h>

#define N_EXPERTS 32
#define K_SEL 4
#define IN_C 1024
#define OUT_C 1024
#define BATCH 4096
#define NTOK (BATCH * K_SEL)   // 16384

#define BM 128
#define MAX_TILES (N_EXPERTS + NTOK / BM)   // fallback table sizing

// workspace layout: xb (bf16) then ctrl ints
#define XB_ELEMS (BATCH * IN_C)                      // 4,194,304
#define CTRL_OFF_BYTES ((size_t)XB_ELEMS * 2)

// main-path ctrl layout
#define MS_EBASE 0                          // 32 ints: per-expert rowlist base
#define MS_ECNT 32                          // 32 ints: per-expert count
#define MS_ROWLIST 64
#define MS_INTS (MS_ROWLIST + NTOK)
// fallback layout (independent)
#define WS_NTILES 0
#define WS_TABLE 8
#define WS_ROWLIST (WS_TABLE + MAX_TILES * 4)
#define CTRL_INTS (WS_ROWLIST + NTOK)
#define WS_COUNTS (CTRL_INTS)
#define WS_CURSOR (CTRL_INTS + 32)

typedef __attribute__((ext_vector_type(4))) float f32x4;
typedef __attribute__((ext_vector_type(8))) short bf16x8;
typedef __attribute__((ext_vector_type(8))) unsigned short u16x8;

__device__ __forceinline__ unsigned short f2bf(float f) {
    union { float f; unsigned u; } v; v.f = f;
    unsigned r = v.u + 0x7fffu + ((v.u >> 16) & 1u);   // RNE
    return (unsigned short)(r >> 16);
}

// ---------------- prep: bucket (bid 0) + xconv ----------------

#define XCONV_B0 1
#define XCONV_NB (XB_ELEMS / 2048)          // 2048
#define PREP_NWG (XCONV_B0 + XCONV_NB)      // 2049

__global__ __launch_bounds__(256)
void prep_kernel(const float* __restrict__ x, const int* __restrict__ idx,
                 unsigned short* __restrict__ xb, int* __restrict__ ctrl) {
    const int bid = blockIdx.x;
    const int t = threadIdx.x;

    if (bid >= XCONV_B0) {
        int i = ((bid - XCONV_B0) * 256 + t) << 3;
        f32x4 v0 = *(const f32x4*)(x + i);
        f32x4 v1 = *(const f32x4*)(x + i + 4);
        u16x8 o;
        o[0] = f2bf(v0[0]); o[1] = f2bf(v0[1]); o[2] = f2bf(v0[2]); o[3] = f2bf(v0[3]);
        o[4] = f2bf(v1[0]); o[5] = f2bf(v1[1]); o[6] = f2bf(v1[2]); o[7] = f2bf(v1[3]);
        *(u16x8*)(xb + i) = o;
    } else {
        __shared__ int cnt[N_EXPERTS], base[N_EXPERTS];
        if (t < N_EXPERTS) cnt[t] = 0;
        __syncthreads();
        #pragma unroll 4
        for (int i = 0; i < NTOK / 256; ++i) {
            int e = idx[i * 256 + t] & (N_EXPERTS - 1);
            atomicAdd(&cnt[e], 1);
        }
        __syncthreads();
        if (t == 0) {
            int off = 0;
            for (int e = 0; e < N_EXPERTS; ++e) { base[e] = off; off += cnt[e]; }
        }
        __syncthreads();
        if (t < N_EXPERTS) {
            ctrl[MS_EBASE + t] = base[t];
            ctrl[MS_ECNT + t] = cnt[t];
            cnt[t] = base[t];               // becomes scatter cursor
        }
        __syncthreads();
        #pragma unroll 4
        for (int i = 0; i < NTOK / 256; ++i) {
            int s = i * 256 + t;
            int e = idx[s] & (N_EXPERTS - 1);
            int p = atomicAdd(&cnt[e], 1);
            ctrl[MS_ROWLIST + p] = s;
        }
    }
}

// ---- grouped GEMM: LDS-resident panel + BARRIER-FREE per-wave compute ----
// Block = (expert e, 64-col slice). Phase 1: panel -> Bp (R13-verified fill).
// Phase 2: waves independent; A frags global->reg (1-step prefetch); B from Bp.

#define GEMM_NWG (N_EXPERTS * 16)           // 512

__global__ __launch_bounds__(512, 1)
void gemm_kernel(const unsigned short* __restrict__ xb,
                 const float* __restrict__ w,
                 const float* __restrict__ bias,
                 const int* __restrict__ ctrl,
                 float* __restrict__ out) {
    const int bid = (int)blockIdx.x;
    const int swz = (bid & 7) * (GEMM_NWG / 8) + (bid >> 3);   // expert-clustered
    const int e  = swz >> 4;
    const int n0 = (swz & 15) << 6;

    __shared__ unsigned short Bp[64 * 1024];   // 128 KB: [n][k], chunk-XOR swizzled

    const int t = threadIdx.x;
    const int lane = t & 63, wv = t >> 6;

    // ---- phase 1: W panel -> Bp (byte-identical to verified R13 fill) ----
    {
        const int q = t & 15, o = t >> 4;       // n-quad, k-octet (0..31)
        const float* wsrc = w + ((size_t)e << 20) + ((size_t)(o << 3) << 10) + n0 + (q << 2);
        #pragma unroll
        for (int p = 0; p < 4; ++p) {
            f32x4 r[8];
            const float* s_ = wsrc + ((size_t)p << 18);
            #pragma unroll
            for (int rr = 0; rr < 8; ++rr) r[rr] = *(const f32x4*)(s_ + ((size_t)rr << 10));
            const int c = (p << 5) + o, chi = c >> 3, clo = c & 7;
            #pragma unroll
            for (int j = 0; j < 4; ++j) {
                const int n = (q << 2) + j;
                const int kap = (n & 7) ^ ((n >> 3) & 7);
                u16x8 ov;
                #pragma unroll
                for (int rr = 0; rr < 8; ++rr) ov[rr] = f2bf(r[rr][j]);
                *(u16x8*)&Bp[(n << 10) + (((chi << 3) | (clo ^ kap)) << 3)] = ov;
            }
        }
    }
    __syncthreads();   // Bp ready — the ONLY block-wide barrier

    const int ebase = ctrl[MS_EBASE + e];
    const int ecnt  = ctrl[MS_ECNT + e];
    if (ecnt == 0) return;
    const int ntile = (ecnt + 31) >> 5;

    const int lrow = lane & 15, lq = lane >> 4;

    // B fragment pointers/offsets (R13-verified math)
    const int n_0 = lrow, n_1 = 16 + lrow, n_2 = 32 + lrow, n_3 = 48 + lrow;
    const char* bp0 = (const char*)&Bp[n_0 << 10];
    const char* bp1 = (const char*)&Bp[n_1 << 10];
    const char* bp2 = (const char*)&Bp[n_2 << 10];
    const char* bp3 = (const char*)&Bp[n_3 << 10];
    const int bx00 = ((lq)     ^ (n_0 & 7) ^ ((n_0 >> 3) & 7)) << 4;
    const int bx01 = ((lq)     ^ (n_1 & 7) ^ ((n_1 >> 3) & 7)) << 4;
    const int bx02 = ((lq)     ^ (n_2 & 7) ^ ((n_2 >> 3) & 7)) << 4;
    const int bx03 = ((lq)     ^ (n_3 & 7) ^ ((n_3 >> 3) & 7)) << 4;
    const int bx10 = ((4 + lq) ^ (n_0 & 7) ^ ((n_0 >> 3) & 7)) << 4;
    const int bx11 = ((4 + lq) ^ (n_1 & 7) ^ ((n_1 >> 3) & 7)) << 4;
    const int bx12 = ((4 + lq) ^ (n_2 & 7) ^ ((n_2 >> 3) & 7)) << 4;
    const int bx13 = ((4 + lq) ^ (n_3 & 7) ^ ((n_3 >> 3) & 7)) << 4;
    const float bc0 = bias[(e << 10) + n0 + n_0];
    const float bc1 = bias[(e << 10) + n0 + n_1];
    const float bc2 = bias[(e << 10) + n0 + n_2];
    const float bc3 = bias[(e << 10) + n0 + n_3];

#define LOADA(P00, P01, P10, P11, KS) {                                        \
    const int kb_ = (KS) << 6;                                                 \
    P00 = *(const bf16x8*)(a0 + kb_);                                          \
    P01 = *(const bf16x8*)(a0 + kb_ + 32);                                     \
    P10 = *(const bf16x8*)(a1 + kb_);                                          \
    P11 = *(const bf16x8*)(a1 + kb_ + 32); }

#define COMPUTE(A00, A01, A10, A11, KS) {                                      \
    const int kso_ = (KS) << 7;                                                \
    bf16x8 b0 = *(const bf16x8*)(bp0 + kso_ + bx00);                           \
    bf16x8 b1 = *(const bf16x8*)(bp1 + kso_ + bx01);                           \
    bf16x8 b2 = *(const bf16x8*)(bp2 + kso_ + bx02);                           \
    bf16x8 b3 = *(const bf16x8*)(bp3 + kso_ + bx03);                           \
    acc00 = __builtin_amdgcn_mfma_f32_16x16x32_bf16(A00, b0, acc00, 0, 0, 0);  \
    acc01 = __builtin_amdgcn_mfma_f32_16x16x32_bf16(A00, b1, acc01, 0, 0, 0);  \
    acc02 = __builtin_amdgcn_mfma_f32_16x16x32_bf16(A00, b2, acc02, 0, 0, 0);  \
    acc03 = __builtin_amdgcn_mfma_f32_16x16x32_bf16(A00, b3, acc03, 0, 0, 0);  \
    acc10 = __builtin_amdgcn_mfma_f32_16x16x32_bf16(A10, b0, acc10, 0, 0, 0);  \
    acc11 = __builtin_amdgcn_mfma_f32_16x16x32_bf16(A10, b1, acc11, 0, 0, 0);  \
    acc12 = __builtin_amdgcn_mfma_f32_16x16x32_bf16(A10, b2, acc12, 0, 0, 0);  \
    acc13 = __builtin_amdgcn_mfma_f32_16x16x32_bf16(A10, b3, acc13, 0, 0, 0);  \
    b0 = *(const bf16x8*)(bp0 + kso_ + bx10);                                  \
    b1 = *(const bf16x8*)(bp1 + kso_ + bx11);                                  \
    b2 = *(const bf16x8*)(bp2 + kso_ + bx12);                                  \
    b3 = *(const bf16x8*)(bp3 + kso_ + bx13);                                  \
    acc00 = __builtin_amdgcn_mfma_f32_16x16x32_bf16(A01, b0, acc00, 0, 0, 0);  \
    acc01 = __builtin_amdgcn_mfma_f32_16x16x32_bf16(A01, b1, acc01, 0, 0, 0);  \
    acc02 = __builtin_amdgcn_mfma_f32_16x16x32_bf16(A01, b2, acc02, 0, 0, 0);  \
    acc03 = __builtin_amdgcn_mfma_f32_16x16x32_bf16(A01, b3, acc03, 0, 0, 0);  \
    acc10 = __builtin_amdgcn_mfma_f32_16x16x32_bf16(A11, b0, acc10, 0, 0, 0);  \
    acc11 = __builtin_amdgcn_mfma_f32_16x16x32_bf16(A11, b1, acc11, 0, 0, 0);  \
    acc12 = __builtin_amdgcn_mfma_f32_16x16x32_bf16(A11, b2, acc12, 0, 0, 0);  \
    acc13 = __builtin_amdgcn_mfma_f32_16x16x32_bf16(A11, b3, acc13, 0, 0, 0); }

#define EPI(M, AC0, AC1, AC2, AC3) {                                           \
    _Pragma("unroll")                                                          \
    for (int j = 0; j < 4; ++j) {                                              \
        int rloc = ((M) << 4) + (lq << 2) + j;                                 \
        if (rloc < rcap) {                                                     \
            int s = ctrl[MS_ROWLIST + base + rloc];                            \
            float* orow = out + ((size_t)s << 10) + n0;                        \
            float v0 = AC0[j] + bc0; orow[lrow]      = v0 > 0.f ? v0 : 0.f;    \
            float v1 = AC1[j] + bc1; orow[16 + lrow] = v1 > 0.f ? v1 : 0.f;    \
            float v2 = AC2[j] + bc2; orow[32 + lrow] = v2 > 0.f ? v2 : 0.f;    \
            float v3 = AC3[j] + bc3; orow[48 + lrow] = v3 > 0.f ? v3 : 0.f;    \
        }                                                                      \
    } }

    // ---- phase 2: independent waves over 32-row m-tiles, no barriers ----
    for (int mt = wv; mt < ntile; mt += 8) {
        const int base = ebase + (mt << 5);
        const int rem = ecnt - (mt << 5);
        const int rcap = rem < 32 ? rem : 32;
        const int r0 = lrow < rcap ? lrow : rcap - 1;
        const int r1 = (16 + lrow) < rcap ? (16 + lrow) : rcap - 1;
        const unsigned short* a0 = xb + ((size_t)(ctrl[MS_ROWLIST + base + r0] >> 2) << 10) + (lq << 3);
        const unsigned short* a1 = xb + ((size_t)(ctrl[MS_ROWLIST + base + r1] >> 2) << 10) + (lq << 3);

        f32x4 acc00 = (f32x4)0.f, acc01 = (f32x4)0.f, acc02 = (f32x4)0.f, acc03 = (f32x4)0.f;
        f32x4 acc10 = (f32x4)0.f, acc11 = (f32x4)0.f, acc12 = (f32x4)0.f, acc13 = (f32x4)0.f;

        bf16x8 p00, p01, p10, p11, q00, q01, q10, q11;
        LOADA(p00, p01, p10, p11, 0);
        #pragma unroll
        for (int ks = 0; ks < 16; ks += 2) {
            LOADA(q00, q01, q10, q11, ks + 1);
            COMPUTE(p00, p01, p10, p11, ks);
            if (ks + 2 < 16) LOADA(p00, p01, p10, p11, ks + 2);
            COMPUTE(q00, q01, q10, q11, ks + 1);
        }

        EPI(0, acc00, acc01, acc02, acc03);
        EPI(1, acc10, acc11, acc12, acc13);
    }
}

// ---------------- fallback f32 path (round-1 proven) for small ws ----------------

__global__ void count_kernel(const int* __restrict__ idx, int* __restrict__ ctrl) {
    int s = blockIdx.x * blockDim.x + threadIdx.x;
    if (s < NTOK) atomicAdd(&ctrl[WS_COUNTS + (idx[s] & (N_EXPERTS - 1))], 1);
}

__global__ void scan_kernel(int* __restrict__ ctrl) {
    if (threadIdx.x != 0) return;
    int off = 0, tiles = 0;
    for (int e = 0; e < N_EXPERTS; ++e) {
        int c = ctrl[WS_COUNTS + e];
        ctrl[WS_CURSOR + e] = off;
        for (int t = 0; t < c; t += BM) {
            ctrl[WS_TABLE + tiles * 4 + 0] = e;
            ctrl[WS_TABLE + tiles * 4 + 1] = off + t;
            ctrl[WS_TABLE + tiles * 4 + 2] = (c - t) < BM ? (c - t) : BM;
            ++tiles;
        }
        off += c;
    }
    ctrl[WS_NTILES] = tiles;
}

__global__ void scatter_kernel(const int* __restrict__ idx, int* __restrict__ ctrl) {
    int s = blockIdx.x * blockDim.x + threadIdx.x;
    if (s < NTOK) {
        int e = idx[s] & (N_EXPERTS - 1);
        int p = atomicAdd(&ctrl[WS_CURSOR + e], 1);
        ctrl[WS_ROWLIST + p] = s;
    }
}

__global__ __launch_bounds__(256, 2)
void gemm_f32_kernel(const float* __restrict__ x, const float* __restrict__ w,
                     const float* __restrict__ bias, const int* __restrict__ ctrl,
                     float* __restrict__ out) {
    int ntiles = ctrl[WS_NTILES];
    if ((int)blockIdx.x >= ntiles) return;
    const int e     = ctrl[WS_TABLE + blockIdx.x * 4 + 0];
    const int list0 = ctrl[WS_TABLE + blockIdx.x * 4 + 1];
    const int nrows = ctrl[WS_TABLE + blockIdx.x * 4 + 2];
    const int n0 = blockIdx.y * 128;

    __shared__ unsigned short As2[BM][40];
    __shared__ unsigned short Bs2[128][40];
    __shared__ int rowtok[BM];

    const int t = threadIdx.x;
    if (t < BM) {
        int r = t < nrows ? t : nrows - 1;
        rowtok[t] = ctrl[WS_ROWLIST + list0 + r];
    }
    __syncthreads();

    const int arow = t >> 1, acol0 = (t & 1) * 16;
    const int brow = t >> 3, bcol0 = (t & 7) * 16;
    const float* xbase = x + (size_t)(rowtok[arow] >> 2) * IN_C + acol0;
    const float* wbase = w + (size_t)e * IN_C * OUT_C + (size_t)brow * OUT_C + n0 + bcol0;

    const int lane = t & 63, wid = t >> 6;
    const int wr = wid >> 1, wc = wid & 1;
    const int lrow = lane & 15, lq = lane >> 4;

    f32x4 acc[4][4];
    #pragma unroll
    for (int m = 0; m < 4; ++m)
        #pragma unroll
        for (int n = 0; n < 4; ++n) acc[m][n] = (f32x4)0.f;

    for (int k0 = 0; k0 < IN_C; k0 += 32) {
        __syncthreads();
        #pragma unroll
        for (int u = 0; u < 4; ++u) {
            f32x4 v = *(const f32x4*)(xbase + k0 + 4 * u);
            ushort4 pk;
            pk.x = f2bf(v[0]); pk.y = f2bf(v[1]); pk.z = f2bf(v[2]); pk.w = f2bf(v[3]);
            *(ushort4*)&As2[arow][acol0 + 4 * u] = pk;
        }
        #pragma unroll
        for (int u = 0; u < 4; ++u) {
            f32x4 v = *(const f32x4*)(wbase + (size_t)k0 * OUT_C + 4 * u);
            Bs2[bcol0 + 4 * u + 0][brow] = f2bf(v[0]);
            Bs2[bcol0 + 4 * u + 1][brow] = f2bf(v[1]);
            Bs2[bcol0 + 4 * u + 2][brow] = f2bf(v[2]);
            Bs2[bcol0 + 4 * u + 3][brow] = f2bf(v[3]);
        }
        __syncthreads();

        bf16x8 a[4], b[4];
        #pragma unroll
        for (int m = 0; m < 4; ++m) a[m] = *(const bf16x8*)&As2[wr * 64 + m * 16 + lrow][lq * 8];
        #pragma unroll
        for (int n = 0; n < 4; ++n) b[n] = *(const bf16x8*)&Bs2[wc * 64 + n * 16 + lrow][lq * 8];
        #pragma unroll
        for (int m = 0; m < 4; ++m)
            #pragma unroll
            for (int n = 0; n < 4; ++n)
                acc[m][n] = __builtin_amdgcn_mfma_f32_16x16x32_bf16(a[m], b[n], acc[m][n], 0, 0, 0);
    }

    #pragma unroll
    for (int m = 0; m < 4; ++m) {
        #pragma unroll
        for (int j = 0; j < 4; ++j) {
            int row = wr * 64 + m * 16 + lq * 4 + j;
            if (row < nrows) {
                int s = rowtok[row];
                float* orow = out + (size_t)s * OUT_C;
                #pragma unroll
                for (int n = 0; n < 4; ++n) {
                    int col = n0 + wc * 64 + n * 16 + lrow;
                    float vv = acc[m][n][j] + bias[e * OUT_C + col];
                    orow[col] = vv > 0.f ? vv : 0.f;
                }
            }
        }
    }
}

// ---------------- launch ----------------

extern "C" void kernel_launch(void* const* d_in, const int* in_sizes, int n_in,
                              void* d_out, int out_size, void* d_ws, size_t ws_size,
                              hipStream_t stream) {
    const float* x    = (const float*)d_in[0];
    const int*   idx  = (const int*)d_in[1];
    const float* w    = (const float*)d_in[2];
    const float* bias = (const float*)d_in[3];
    float* out = (float*)d_out;

    const size_t need = CTRL_OFF_BYTES + (size_t)(CTRL_INTS + 64) * sizeof(int);
    if (ws_size >= need) {
        unsigned short* xb = (unsigned short*)d_ws;
        int* ctrl = (int*)((char*)d_ws + CTRL_OFF_BYTES);

        prep_kernel<<<PREP_NWG, 256, 0, stream>>>(x, idx, xb, ctrl);
        gemm_kernel<<<GEMM_NWG, 512, 0, stream>>>(xb, w, bias, ctrl, out);
    } else {
        int* ctrl = (int*)d_ws;
        hipMemsetAsync(ctrl, 0, (CTRL_INTS + 64) * sizeof(int), stream);
        count_kernel<<<NTOK / 256, 256, 0, stream>>>(idx, ctrl);
        scan_kernel<<<1, 64, 0, stream>>>(ctrl);
        scatter_kernel<<<NTOK / 256, 256, 0, stream>>>(idx, ctrl);
        dim3 grid(MAX_TILES, OUT_C / 128);
        gemm_f32_kernel<<<grid, 256, 0, stream>>>(x, w, bias, ctrl, out);
    }
}

// Round 16
// 209.249 us; speedup vs baseline: 1.7804x; 1.6502x over previous
//
#include <hip/hip_runtime.h>
#include <hip/hip_bf16.h>

#define N_EXPERTS 32
#define K_SEL 4
#define IN_C 1024
#define OUT_C 1024
#define BATCH 4096
#define NTOK (BATCH * K_SEL)   // 16384

#define BM 128
#define BN 128
#define BK 64
#define MAX_TILES (N_EXPERTS + NTOK / BM)   // 160 worst case

// workspace layout: xb (bf16) then ctrl ints
#define XB_ELEMS (BATCH * IN_C)                      // 4,194,304
#define CTRL_OFF_BYTES ((size_t)XB_ELEMS * 2)

#define WS_NTILES 0
#define WS_TABLE 8                          // 4 ints per tile
#define WS_ROWLIST (WS_TABLE + MAX_TILES * 4)
#define CTRL_INTS (WS_ROWLIST + NTOK)
// fallback layout additions
#define WS_COUNTS (CTRL_INTS)
#define WS_CURSOR (CTRL_INTS + 32)

typedef __attribute__((ext_vector_type(4))) float f32x4;
typedef __attribute__((ext_vector_type(8))) short bf16x8;
typedef __attribute__((ext_vector_type(8))) unsigned short u16x8;

__device__ __forceinline__ unsigned short f2bf(float f) {
    union { float f; unsigned u; } v; v.f = f;
    unsigned r = v.u + 0x7fffu + ((v.u >> 16) & 1u);   // RNE
    return (unsigned short)(r >> 16);
}

__device__ __forceinline__ void gload16(const void* g, void* l) {
    __builtin_amdgcn_global_load_lds(
        (const __attribute__((address_space(1))) unsigned int*)g,
        (__attribute__((address_space(3))) unsigned int*)l, 16, 0, 0);
}

// ---------------- prep: bucket (bid 0) + xconv ----------------

#define XCONV_B0 1
#define XCONV_NB (XB_ELEMS / 2048)          // 2048
#define PREP_NWG (XCONV_B0 + XCONV_NB)      // 2049

__global__ __launch_bounds__(256)
void prep_kernel(const float* __restrict__ x, const int* __restrict__ idx,
                 unsigned short* __restrict__ xb, int* __restrict__ ctrl) {
    const int bid = blockIdx.x;
    const int t = threadIdx.x;

    if (bid >= XCONV_B0) {
        int i = ((bid - XCONV_B0) * 256 + t) << 3;
        f32x4 v0 = *(const f32x4*)(x + i);
        f32x4 v1 = *(const f32x4*)(x + i + 4);
        u16x8 o;
        o[0] = f2bf(v0[0]); o[1] = f2bf(v0[1]); o[2] = f2bf(v0[2]); o[3] = f2bf(v0[3]);
        o[4] = f2bf(v1[0]); o[5] = f2bf(v1[1]); o[6] = f2bf(v1[2]); o[7] = f2bf(v1[3]);
        *(u16x8*)(xb + i) = o;
    } else {
        __shared__ int cnt[N_EXPERTS], base[N_EXPERTS], tbase[N_EXPERTS];
        if (t < N_EXPERTS) cnt[t] = 0;
        __syncthreads();
        #pragma unroll 4
        for (int i = 0; i < NTOK / 256; ++i) {
            int e = idx[i * 256 + t] & (N_EXPERTS - 1);
            atomicAdd(&cnt[e], 1);
        }
        __syncthreads();
        if (t == 0) {
            int off = 0, tiles = 0;
            for (int e = 0; e < N_EXPERTS; ++e) {
                base[e] = off;
                tbase[e] = tiles;
                int c = cnt[e];
                tiles += (c + BM - 1) / BM;
                off += c;
            }
            ctrl[WS_NTILES] = tiles;
        }
        __syncthreads();
        if (t < N_EXPERTS) {
            int c = cnt[t], off = base[t], tt = tbase[t];
            for (int u = 0; u < c; u += BM, ++tt) {
                ctrl[WS_TABLE + tt * 4 + 0] = t;
                ctrl[WS_TABLE + tt * 4 + 1] = off + u;
                ctrl[WS_TABLE + tt * 4 + 2] = (c - u) < BM ? (c - u) : BM;
            }
            cnt[t] = off;   // becomes scatter cursor
        }
        __syncthreads();
        #pragma unroll 4
        for (int i = 0; i < NTOK / 256; ++i) {
            int s = i * 256 + t;
            int e = idx[s] & (N_EXPERTS - 1);
            int p = atomicAdd(&cnt[e], 1);
            ctrl[WS_ROWLIST + p] = s;
        }
    }
}

// -------- fused bf16 grouped GEMM (R7 base, 4-blocks/CU occupancy target) --------

__global__ __launch_bounds__(256, 4)
void gemm_kernel(const unsigned short* __restrict__ xb,
                 const float* __restrict__ w,
                 const float* __restrict__ bias,
                 const int* __restrict__ ctrl,
                 float* __restrict__ out) {
    // expert-clustered XCD swizzle: XCD j owns tiles [20j, 20j+20), nb-fastest
    const int swz = ((int)blockIdx.x & 7) * ((MAX_TILES * 8) >> 3) + ((int)blockIdx.x >> 3);
    const int tileIdx = swz >> 3;
    const int ntiles = ctrl[WS_NTILES];
    if (tileIdx >= ntiles) return;
    const int e     = ctrl[WS_TABLE + tileIdx * 4 + 0];
    const int list0 = ctrl[WS_TABLE + tileIdx * 4 + 1];
    const int nrows = ctrl[WS_TABLE + tileIdx * 4 + 2];
    const int n0 = (swz & 7) * BN;

    __shared__ unsigned short As[BM][BK];   // linear; chunk-swizzled via A-source perm
    __shared__ unsigned short Bs[BN][BK];   // rows = n; chunk phys = o ^ (n&7) ^ ((n>>3)&7)
    __shared__ int rowtok[BM];

    const int t = threadIdx.x;
    const int lane = t & 63, wv = t >> 6;

    if (t < BM) {
        int r = t < nrows ? t : nrows - 1;
        rowtok[t] = ctrl[WS_ROWLIST + list0 + r];
    }
    __syncthreads();

    // A staging (proven path): source chunk pre-swizzled
    const int cg = (lane & 7) ^ (lane >> 3);
    const unsigned short* asrc[4];
    #pragma unroll
    for (int i = 0; i < 4; ++i) {
        int row = (wv << 5) + (i << 3) + (lane >> 3);
        asrc[i] = xb + (size_t)(rowtok[row] >> 2) * IN_C + (cg << 3);
    }

    // B staging roles: q = n-quad (4 consecutive n), o = k-octet
    const int q = t & 31, o = t >> 5;
    const float* bbase = w + ((size_t)e << 20) + ((size_t)(o << 3) << 10) + n0 + (q << 2);

    const int wr = (t >> 7) & 1;          // 2x2 wave grid, 64x64 per wave
    const int wc = (t >> 6) & 1;
    const int lrow = lane & 15, lq = lane >> 4;
    const int afo0 = ((lq) ^ (lrow & 7)) << 4;
    const int afo1 = ((4 + lq) ^ (lrow & 7)) << 4;
    const char* aB = (const char*)&As[wr * 64 + lrow][0];
    const char* bB = (const char*)&Bs[wc * 64 + lrow][0];
    int bfo[2][4];
    #pragma unroll
    for (int kk = 0; kk < 2; ++kk)
        #pragma unroll
        for (int nf = 0; nf < 4; ++nf)
            bfo[kk][nf] = ((((kk << 2) + lq) ^ (lrow & 7) ^ ((2 * nf + (lrow >> 3)) & 7)) << 4);

    f32x4 acc[4][4];
    #pragma unroll
    for (int m = 0; m < 4; ++m)
        #pragma unroll
        for (int n = 0; n < 4; ++n) acc[m][n] = (f32x4)0.f;

    // prologue: B(k=0) loads in flight
    f32x4 breg[8];
    #pragma unroll
    for (int r = 0; r < 8; ++r)
        breg[r] = *(const f32x4*)(bbase + ((size_t)r << 10));

    for (int k0 = 0; k0 < IN_C; k0 += BK) {
        // barrier #1: all waves finished LDS reads of prior step
        asm volatile("s_waitcnt lgkmcnt(0)" ::: "memory");
        __builtin_amdgcn_s_barrier();
        // A direct-to-LDS (4 VMEM ops; stay in flight past the B write)
        #pragma unroll
        for (int i = 0; i < 4; ++i)
            gload16(asrc[i] + k0, &As[(wv << 5) + (i << 3)][0]);
        __builtin_amdgcn_sched_barrier(0);
        // convert B(k) -> Bs (compiler auto-waits for the 8 B(k) loads; A stays in flight)
        #pragma unroll
        for (int j = 0; j < 4; ++j) {
            const int n = (q << 2) + j;
            const int phys = o ^ (n & 7) ^ ((n >> 3) & 7);
            u16x8 ov;
            #pragma unroll
            for (int r = 0; r < 8; ++r) ov[r] = f2bf(breg[r][j]);
            *(u16x8*)&Bs[n][phys << 3] = ov;
        }
        __builtin_amdgcn_sched_barrier(0);
        if (k0 + BK < IN_C) {
            // prefetch B(k+1); 8 loads stay in flight across the barrier
            const float* bs2 = bbase + ((size_t)(k0 + BK) << 10);
            #pragma unroll
            for (int r = 0; r < 8; ++r)
                breg[r] = *(const f32x4*)(bs2 + ((size_t)r << 10));
            __builtin_amdgcn_sched_barrier(0);
            asm volatile("s_waitcnt vmcnt(8)" ::: "memory");   // A done, B(k+1) in flight
        } else {
            asm volatile("s_waitcnt vmcnt(0)" ::: "memory");   // last tile: drain A
        }
        asm volatile("s_waitcnt lgkmcnt(0)" ::: "memory");
        __builtin_amdgcn_sched_barrier(0);
        __builtin_amdgcn_s_barrier();      // barrier #2: tile ready
        #pragma unroll
        for (int kk = 0; kk < 2; ++kk) {
            const int afo = kk ? afo1 : afo0;
            bf16x8 a[4], b[4];
            #pragma unroll
            for (int m = 0; m < 4; ++m) a[m] = *(const bf16x8*)(aB + m * 2048 + afo);
            #pragma unroll
            for (int n = 0; n < 4; ++n) b[n] = *(const bf16x8*)(bB + n * 2048 + bfo[kk][n]);
            #pragma unroll
            for (int m = 0; m < 4; ++m)
                #pragma unroll
                for (int n = 0; n < 4; ++n)
                    acc[m][n] = __builtin_amdgcn_mfma_f32_16x16x32_bf16(a[m], b[n], acc[m][n], 0, 0, 0);
        }
    }

    // C/D layout: col = lane&15, row = (lane>>4)*4 + j   [verified m89/m91]
    #pragma unroll
    for (int m = 0; m < 4; ++m) {
        #pragma unroll
        for (int j = 0; j < 4; ++j) {
            int row = wr * 64 + m * 16 + lq * 4 + j;
            if (row < nrows) {
                int s = rowtok[row];
                float* orow = out + (size_t)s * OUT_C;
                #pragma unroll
                for (int n = 0; n < 4; ++n) {
                    int col = n0 + wc * 64 + n * 16 + lrow;
                    float vv = acc[m][n][j] + bias[e * OUT_C + col];
                    orow[col] = vv > 0.f ? vv : 0.f;
                }
            }
        }
    }
}

// ---------------- fallback f32 path (round-1 proven) for small ws ----------------

__global__ void count_kernel(const int* __restrict__ idx, int* __restrict__ ctrl) {
    int s = blockIdx.x * blockDim.x + threadIdx.x;
    if (s < NTOK) atomicAdd(&ctrl[WS_COUNTS + (idx[s] & (N_EXPERTS - 1))], 1);
}

__global__ void scan_kernel(int* __restrict__ ctrl) {
    if (threadIdx.x != 0) return;
    int off = 0, tiles = 0;
    for (int e = 0; e < N_EXPERTS; ++e) {
        int c = ctrl[WS_COUNTS + e];
        ctrl[WS_CURSOR + e] = off;
        for (int t = 0; t < c; t += BM) {
            ctrl[WS_TABLE + tiles * 4 + 0] = e;
            ctrl[WS_TABLE + tiles * 4 + 1] = off + t;
            ctrl[WS_TABLE + tiles * 4 + 2] = (c - t) < BM ? (c - t) : BM;
            ++tiles;
        }
        off += c;
    }
    ctrl[WS_NTILES] = tiles;
}

__global__ void scatter_kernel(const int* __restrict__ idx, int* __restrict__ ctrl) {
    int s = blockIdx.x * blockDim.x + threadIdx.x;
    if (s < NTOK) {
        int e = idx[s] & (N_EXPERTS - 1);
        int p = atomicAdd(&ctrl[WS_CURSOR + e], 1);
        ctrl[WS_ROWLIST + p] = s;
    }
}

__global__ __launch_bounds__(256, 2)
void gemm_f32_kernel(const float* __restrict__ x, const float* __restrict__ w,
                     const float* __restrict__ bias, const int* __restrict__ ctrl,
                     float* __restrict__ out) {
    int ntiles = ctrl[WS_NTILES];
    if ((int)blockIdx.x >= ntiles) return;
    const int e     = ctrl[WS_TABLE + blockIdx.x * 4 + 0];
    const int list0 = ctrl[WS_TABLE + blockIdx.x * 4 + 1];
    const int nrows = ctrl[WS_TABLE + blockIdx.x * 4 + 2];
    const int n0 = blockIdx.y * BN;

    __shared__ unsigned short As2[BM][40];
    __shared__ unsigned short Bs2[BN][40];
    __shared__ int rowtok[BM];

    const int t = threadIdx.x;
    if (t < BM) {
        int r = t < nrows ? t : nrows - 1;
        rowtok[t] = ctrl[WS_ROWLIST + list0 + r];
    }
    __syncthreads();

    const int arow = t >> 1, acol0 = (t & 1) * 16;
    const int brow = t >> 3, bcol0 = (t & 7) * 16;
    const float* xbase = x + (size_t)(rowtok[arow] >> 2) * IN_C + acol0;
    const float* wbase = w + (size_t)e * IN_C * OUT_C + (size_t)brow * OUT_C + n0 + bcol0;

    const int lane = t & 63, wid = t >> 6;
    const int wr = wid >> 1, wc = wid & 1;
    const int lrow = lane & 15, lq = lane >> 4;

    f32x4 acc[4][4];
    #pragma unroll
    for (int m = 0; m < 4; ++m)
        #pragma unroll
        for (int n = 0; n < 4; ++n) acc[m][n] = (f32x4)0.f;

    for (int k0 = 0; k0 < IN_C; k0 += 32) {
        __syncthreads();
        #pragma unroll
        for (int u = 0; u < 4; ++u) {
            f32x4 v = *(const f32x4*)(xbase + k0 + 4 * u);
            ushort4 pk;
            pk.x = f2bf(v[0]); pk.y = f2bf(v[1]); pk.z = f2bf(v[2]); pk.w = f2bf(v[3]);
            *(ushort4*)&As2[arow][acol0 + 4 * u] = pk;
        }
        #pragma unroll
        for (int u = 0; u < 4; ++u) {
            f32x4 v = *(const f32x4*)(wbase + (size_t)k0 * OUT_C + 4 * u);
            Bs2[bcol0 + 4 * u + 0][brow] = f2bf(v[0]);
            Bs2[bcol0 + 4 * u + 1][brow] = f2bf(v[1]);
            Bs2[bcol0 + 4 * u + 2][brow] = f2bf(v[2]);
            Bs2[bcol0 + 4 * u + 3][brow] = f2bf(v[3]);
        }
        __syncthreads();

        bf16x8 a[4], b[4];
        #pragma unroll
        for (int m = 0; m < 4; ++m) a[m] = *(const bf16x8*)&As2[wr * 64 + m * 16 + lrow][lq * 8];
        #pragma unroll
        for (int n = 0; n < 4; ++n) b[n] = *(const bf16x8*)&Bs2[wc * 64 + n * 16 + lrow][lq * 8];
        #pragma unroll
        for (int m = 0; m < 4; ++m)
            #pragma unroll
            for (int n = 0; n < 4; ++n)
                acc[m][n] = __builtin_amdgcn_mfma_f32_16x16x32_bf16(a[m], b[n], acc[m][n], 0, 0, 0);
    }

    #pragma unroll
    for (int m = 0; m < 4; ++m) {
        #pragma unroll
        for (int j = 0; j < 4; ++j) {
            int row = wr * 64 + m * 16 + lq * 4 + j;
            if (row < nrows) {
                int s = rowtok[row];
                float* orow = out + (size_t)s * OUT_C;
                #pragma unroll
                for (int n = 0; n < 4; ++n) {
                    int col = n0 + wc * 64 + n * 16 + lrow;
                    float vv = acc[m][n][j] + bias[e * OUT_C + col];
                    orow[col] = vv > 0.f ? vv : 0.f;
                }
            }
        }
    }
}

// ---------------- launch ----------------

extern "C" void kernel_launch(void* const* d_in, const int* in_sizes, int n_in,
                              void* d_out, int out_size, void* d_ws, size_t ws_size,
                              hipStream_t stream) {
    const float* x    = (const float*)d_in[0];
    const int*   idx  = (const int*)d_in[1];
    const float* w    = (const float*)d_in[2];
    const float* bias = (const float*)d_in[3];
    float* out = (float*)d_out;

    const size_t need = CTRL_OFF_BYTES + (size_t)(CTRL_INTS + 64) * sizeof(int);
    if (ws_size >= need) {
        unsigned short* xb = (unsigned short*)d_ws;
        int* ctrl = (int*)((char*)d_ws + CTRL_OFF_BYTES);

        prep_kernel<<<PREP_NWG, 256, 0, stream>>>(x, idx, xb, ctrl);
        gemm_kernel<<<MAX_TILES * 8, 256, 0, stream>>>(xb, w, bias, ctrl, out);
    } else {
        int* ctrl = (int*)d_ws;
        hipMemsetAsync(ctrl, 0, (CTRL_INTS + 64) * sizeof(int), stream);
        count_kernel<<<NTOK / 256, 256, 0, stream>>>(idx, ctrl);
        scan_kernel<<<1, 64, 0, stream>>>(ctrl);
        scatter_kernel<<<NTOK / 256, 256, 0, stream>>>(idx, ctrl);
        dim3 grid(MAX_TILES, OUT_C / BN);
        gemm_f32_kernel<<<grid, 256, 0, stream>>>(x, w, bias, ctrl, out);
    }
}

// Round 17
// 104.056 us; speedup vs baseline: 3.5803x; 2.0109x over previous
//
#include <hip/hip_runtime.h>
#include <hip/hip_bf16.h>

#define N_EXPERTS 32
#define K_SEL 4
#define IN_C 1024
#define OUT_C 1024
#define BATCH 4096
#define NTOK (BATCH * K_SEL)   // 16384

#define BM 128
#define BN 128
#define BK 64
#define MAX_TILES (N_EXPERTS + NTOK / BM)   // 160 worst case

// workspace layout: xb (bf16) then ctrl ints
#define XB_ELEMS (BATCH * IN_C)                      // 4,194,304
#define CTRL_OFF_BYTES ((size_t)XB_ELEMS * 2)

#define WS_NTILES 0
#define WS_TABLE 8                          // 4 ints per tile
#define WS_ROWLIST (WS_TABLE + MAX_TILES * 4)
#define CTRL_INTS (WS_ROWLIST + NTOK)
// fallback layout additions
#define WS_COUNTS (CTRL_INTS)
#define WS_CURSOR (CTRL_INTS + 32)

typedef __attribute__((ext_vector_type(4))) float f32x4;
typedef __attribute__((ext_vector_type(8))) short bf16x8;
typedef __attribute__((ext_vector_type(8))) unsigned short u16x8;

__device__ __forceinline__ unsigned short f2bf(float f) {
    union { float f; unsigned u; } v; v.f = f;
    unsigned r = v.u + 0x7fffu + ((v.u >> 16) & 1u);   // RNE
    return (unsigned short)(r >> 16);
}

__device__ __forceinline__ void gload16(const void* g, void* l) {
    __builtin_amdgcn_global_load_lds(
        (const __attribute__((address_space(1))) unsigned int*)g,
        (__attribute__((address_space(3))) unsigned int*)l, 16, 0, 0);
}

// ---------------- prep: bucket (bid 0) + xconv ----------------

#define XCONV_B0 1
#define XCONV_NB (XB_ELEMS / 2048)          // 2048
#define PREP_NWG (XCONV_B0 + XCONV_NB)      // 2049

__global__ __launch_bounds__(256)
void prep_kernel(const float* __restrict__ x, const int* __restrict__ idx,
                 unsigned short* __restrict__ xb, int* __restrict__ ctrl) {
    const int bid = blockIdx.x;
    const int t = threadIdx.x;

    if (bid >= XCONV_B0) {
        int i = ((bid - XCONV_B0) * 256 + t) << 3;
        f32x4 v0 = *(const f32x4*)(x + i);
        f32x4 v1 = *(const f32x4*)(x + i + 4);
        u16x8 o;
        o[0] = f2bf(v0[0]); o[1] = f2bf(v0[1]); o[2] = f2bf(v0[2]); o[3] = f2bf(v0[3]);
        o[4] = f2bf(v1[0]); o[5] = f2bf(v1[1]); o[6] = f2bf(v1[2]); o[7] = f2bf(v1[3]);
        *(u16x8*)(xb + i) = o;
    } else {
        __shared__ int cnt[N_EXPERTS], base[N_EXPERTS], tbase[N_EXPERTS];
        if (t < N_EXPERTS) cnt[t] = 0;
        __syncthreads();
        #pragma unroll 4
        for (int i = 0; i < NTOK / 256; ++i) {
            int e = idx[i * 256 + t] & (N_EXPERTS - 1);
            atomicAdd(&cnt[e], 1);
        }
        __syncthreads();
        if (t == 0) {
            int off = 0, tiles = 0;
            for (int e = 0; e < N_EXPERTS; ++e) {
                base[e] = off;
                tbase[e] = tiles;
                int c = cnt[e];
                tiles += (c + BM - 1) / BM;
                off += c;
            }
            ctrl[WS_NTILES] = tiles;
        }
        __syncthreads();
        if (t < N_EXPERTS) {
            int c = cnt[t], off = base[t], tt = tbase[t];
            for (int u = 0; u < c; u += BM, ++tt) {
                ctrl[WS_TABLE + tt * 4 + 0] = t;
                ctrl[WS_TABLE + tt * 4 + 1] = off + u;
                ctrl[WS_TABLE + tt * 4 + 2] = (c - u) < BM ? (c - u) : BM;
            }
            cnt[t] = off;   // becomes scatter cursor
        }
        __syncthreads();
        #pragma unroll 4
        for (int i = 0; i < NTOK / 256; ++i) {
            int s = i * 256 + t;
            int e = idx[s] & (N_EXPERTS - 1);
            int p = atomicAdd(&cnt[e], 1);
            ctrl[WS_ROWLIST + p] = s;
        }
    }
}

// -------- fused bf16 grouped GEMM (best measured: R7/R10, 104.8 us) --------

__global__ __launch_bounds__(256, 3)
void gemm_kernel(const unsigned short* __restrict__ xb,
                 const float* __restrict__ w,
                 const float* __restrict__ bias,
                 const int* __restrict__ ctrl,
                 float* __restrict__ out) {
    // expert-clustered XCD swizzle: XCD j owns tiles [20j, 20j+20), nb-fastest
    const int swz = ((int)blockIdx.x & 7) * ((MAX_TILES * 8) >> 3) + ((int)blockIdx.x >> 3);
    const int tileIdx = swz >> 3;
    const int ntiles = ctrl[WS_NTILES];
    if (tileIdx >= ntiles) return;
    const int e     = ctrl[WS_TABLE + tileIdx * 4 + 0];
    const int list0 = ctrl[WS_TABLE + tileIdx * 4 + 1];
    const int nrows = ctrl[WS_TABLE + tileIdx * 4 + 2];
    const int n0 = (swz & 7) * BN;

    __shared__ unsigned short As[BM][BK];   // linear; chunk-swizzled via A-source perm
    __shared__ unsigned short Bs[BN][BK];   // rows = n; chunk phys = o ^ (n&7) ^ ((n>>3)&7)
    __shared__ int rowtok[BM];

    const int t = threadIdx.x;
    const int lane = t & 63, wv = t >> 6;

    if (t < BM) {
        int r = t < nrows ? t : nrows - 1;
        rowtok[t] = ctrl[WS_ROWLIST + list0 + r];
    }
    __syncthreads();

    // A staging (proven path): source chunk pre-swizzled
    const int cg = (lane & 7) ^ (lane >> 3);
    const unsigned short* asrc[4];
    #pragma unroll
    for (int i = 0; i < 4; ++i) {
        int row = (wv << 5) + (i << 3) + (lane >> 3);
        asrc[i] = xb + (size_t)(rowtok[row] >> 2) * IN_C + (cg << 3);
    }

    // B staging roles: q = n-quad (4 consecutive n), o = k-octet
    const int q = t & 31, o = t >> 5;
    const float* bbase = w + ((size_t)e << 20) + ((size_t)(o << 3) << 10) + n0 + (q << 2);

    const int wr = (t >> 7) & 1;          // 2x2 wave grid, 64x64 per wave
    const int wc = (t >> 6) & 1;
    const int lrow = lane & 15, lq = lane >> 4;
    const int afo0 = ((lq) ^ (lrow & 7)) << 4;
    const int afo1 = ((4 + lq) ^ (lrow & 7)) << 4;
    const char* aB = (const char*)&As[wr * 64 + lrow][0];
    const char* bB = (const char*)&Bs[wc * 64 + lrow][0];
    int bfo[2][4];
    #pragma unroll
    for (int kk = 0; kk < 2; ++kk)
        #pragma unroll
        for (int nf = 0; nf < 4; ++nf)
            bfo[kk][nf] = ((((kk << 2) + lq) ^ (lrow & 7) ^ ((2 * nf + (lrow >> 3)) & 7)) << 4);

    f32x4 acc[4][4];
    #pragma unroll
    for (int m = 0; m < 4; ++m)
        #pragma unroll
        for (int n = 0; n < 4; ++n) acc[m][n] = (f32x4)0.f;

    // prologue: B(k=0) loads in flight
    f32x4 breg[8];
    #pragma unroll
    for (int r = 0; r < 8; ++r)
        breg[r] = *(const f32x4*)(bbase + ((size_t)r << 10));

    for (int k0 = 0; k0 < IN_C; k0 += BK) {
        // barrier #1: all waves finished LDS reads of prior step
        asm volatile("s_waitcnt lgkmcnt(0)" ::: "memory");
        __builtin_amdgcn_s_barrier();
        // A direct-to-LDS (4 VMEM ops; stay in flight past the B write)
        #pragma unroll
        for (int i = 0; i < 4; ++i)
            gload16(asrc[i] + k0, &As[(wv << 5) + (i << 3)][0]);
        __builtin_amdgcn_sched_barrier(0);
        // convert B(k) -> Bs (compiler auto-waits for the 8 B(k) loads; A stays in flight)
        #pragma unroll
        for (int j = 0; j < 4; ++j) {
            const int n = (q << 2) + j;
            const int phys = o ^ (n & 7) ^ ((n >> 3) & 7);
            u16x8 ov;
            #pragma unroll
            for (int r = 0; r < 8; ++r) ov[r] = f2bf(breg[r][j]);
            *(u16x8*)&Bs[n][phys << 3] = ov;
        }
        __builtin_amdgcn_sched_barrier(0);
        if (k0 + BK < IN_C) {
            // prefetch B(k+1); 8 loads stay in flight across the barrier
            const float* bs2 = bbase + ((size_t)(k0 + BK) << 10);
            #pragma unroll
            for (int r = 0; r < 8; ++r)
                breg[r] = *(const f32x4*)(bs2 + ((size_t)r << 10));
            __builtin_amdgcn_sched_barrier(0);
            asm volatile("s_waitcnt vmcnt(8)" ::: "memory");   // A done, B(k+1) in flight
        } else {
            asm volatile("s_waitcnt vmcnt(0)" ::: "memory");   // last tile: drain A
        }
        asm volatile("s_waitcnt lgkmcnt(0)" ::: "memory");
        __builtin_amdgcn_sched_barrier(0);
        __builtin_amdgcn_s_barrier();      // barrier #2: tile ready
        #pragma unroll
        for (int kk = 0; kk < 2; ++kk) {
            const int afo = kk ? afo1 : afo0;
            bf16x8 a[4], b[4];
            #pragma unroll
            for (int m = 0; m < 4; ++m) a[m] = *(const bf16x8*)(aB + m * 2048 + afo);
            #pragma unroll
            for (int n = 0; n < 4; ++n) b[n] = *(const bf16x8*)(bB + n * 2048 + bfo[kk][n]);
            #pragma unroll
            for (int m = 0; m < 4; ++m)
                #pragma unroll
                for (int n = 0; n < 4; ++n)
                    acc[m][n] = __builtin_amdgcn_mfma_f32_16x16x32_bf16(a[m], b[n], acc[m][n], 0, 0, 0);
        }
    }

    // C/D layout: col = lane&15, row = (lane>>4)*4 + j   [verified m89/m91]
    #pragma unroll
    for (int m = 0; m < 4; ++m) {
        #pragma unroll
        for (int j = 0; j < 4; ++j) {
            int row = wr * 64 + m * 16 + lq * 4 + j;
            if (row < nrows) {
                int s = rowtok[row];
                float* orow = out + (size_t)s * OUT_C;
                #pragma unroll
                for (int n = 0; n < 4; ++n) {
                    int col = n0 + wc * 64 + n * 16 + lrow;
                    float vv = acc[m][n][j] + bias[e * OUT_C + col];
                    orow[col] = vv > 0.f ? vv : 0.f;
                }
            }
        }
    }
}

// ---------------- fallback f32 path (round-1 proven) for small ws ----------------

__global__ void count_kernel(const int* __restrict__ idx, int* __restrict__ ctrl) {
    int s = blockIdx.x * blockDim.x + threadIdx.x;
    if (s < NTOK) atomicAdd(&ctrl[WS_COUNTS + (idx[s] & (N_EXPERTS - 1))], 1);
}

__global__ void scan_kernel(int* __restrict__ ctrl) {
    if (threadIdx.x != 0) return;
    int off = 0, tiles = 0;
    for (int e = 0; e < N_EXPERTS; ++e) {
        int c = ctrl[WS_COUNTS + e];
        ctrl[WS_CURSOR + e] = off;
        for (int t = 0; t < c; t += BM) {
            ctrl[WS_TABLE + tiles * 4 + 0] = e;
            ctrl[WS_TABLE + tiles * 4 + 1] = off + t;
            ctrl[WS_TABLE + tiles * 4 + 2] = (c - t) < BM ? (c - t) : BM;
            ++tiles;
        }
        off += c;
    }
    ctrl[WS_NTILES] = tiles;
}

__global__ void scatter_kernel(const int* __restrict__ idx, int* __restrict__ ctrl) {
    int s = blockIdx.x * blockDim.x + threadIdx.x;
    if (s < NTOK) {
        int e = idx[s] & (N_EXPERTS - 1);
        int p = atomicAdd(&ctrl[WS_CURSOR + e], 1);
        ctrl[WS_ROWLIST + p] = s;
    }
}

__global__ __launch_bounds__(256, 2)
void gemm_f32_kernel(const float* __restrict__ x, const float* __restrict__ w,
                     const float* __restrict__ bias, const int* __restrict__ ctrl,
                     float* __restrict__ out) {
    int ntiles = ctrl[WS_NTILES];
    if ((int)blockIdx.x >= ntiles) return;
    const int e     = ctrl[WS_TABLE + blockIdx.x * 4 + 0];
    const int list0 = ctrl[WS_TABLE + blockIdx.x * 4 + 1];
    const int nrows = ctrl[WS_TABLE + blockIdx.x * 4 + 2];
    const int n0 = blockIdx.y * BN;

    __shared__ unsigned short As2[BM][40];
    __shared__ unsigned short Bs2[BN][40];
    __shared__ int rowtok[BM];

    const int t = threadIdx.x;
    if (t < BM) {
        int r = t < nrows ? t : nrows - 1;
        rowtok[t] = ctrl[WS_ROWLIST + list0 + r];
    }
    __syncthreads();

    const int arow = t >> 1, acol0 = (t & 1) * 16;
    const int brow = t >> 3, bcol0 = (t & 7) * 16;
    const float* xbase = x + (size_t)(rowtok[arow] >> 2) * IN_C + acol0;
    const float* wbase = w + (size_t)e * IN_C * OUT_C + (size_t)brow * OUT_C + n0 + bcol0;

    const int lane = t & 63, wid = t >> 6;
    const int wr = wid >> 1, wc = wid & 1;
    const int lrow = lane & 15, lq = lane >> 4;

    f32x4 acc[4][4];
    #pragma unroll
    for (int m = 0; m < 4; ++m)
        #pragma unroll
        for (int n = 0; n < 4; ++n) acc[m][n] = (f32x4)0.f;

    for (int k0 = 0; k0 < IN_C; k0 += 32) {
        __syncthreads();
        #pragma unroll
        for (int u = 0; u < 4; ++u) {
            f32x4 v = *(const f32x4*)(xbase + k0 + 4 * u);
            ushort4 pk;
            pk.x = f2bf(v[0]); pk.y = f2bf(v[1]); pk.z = f2bf(v[2]); pk.w = f2bf(v[3]);
            *(ushort4*)&As2[arow][acol0 + 4 * u] = pk;
        }
        #pragma unroll
        for (int u = 0; u < 4; ++u) {
            f32x4 v = *(const f32x4*)(wbase + (size_t)k0 * OUT_C + 4 * u);
            Bs2[bcol0 + 4 * u + 0][brow] = f2bf(v[0]);
            Bs2[bcol0 + 4 * u + 1][brow] = f2bf(v[1]);
            Bs2[bcol0 + 4 * u + 2][brow] = f2bf(v[2]);
            Bs2[bcol0 + 4 * u + 3][brow] = f2bf(v[3]);
        }
        __syncthreads();

        bf16x8 a[4], b[4];
        #pragma unroll
        for (int m = 0; m < 4; ++m) a[m] = *(const bf16x8*)&As2[wr * 64 + m * 16 + lrow][lq * 8];
        #pragma unroll
        for (int n = 0; n < 4; ++n) b[n] = *(const bf16x8*)&Bs2[wc * 64 + n * 16 + lrow][lq * 8];
        #pragma unroll
        for (int m = 0; m < 4; ++m)
            #pragma unroll
            for (int n = 0; n < 4; ++n)
                acc[m][n] = __builtin_amdgcn_mfma_f32_16x16x32_bf16(a[m], b[n], acc[m][n], 0, 0, 0);
    }

    #pragma unroll
    for (int m = 0; m < 4; ++m) {
        #pragma unroll
        for (int j = 0; j < 4; ++j) {
            int row = wr * 64 + m * 16 + lq * 4 + j;
            if (row < nrows) {
                int s = rowtok[row];
                float* orow = out + (size_t)s * OUT_C;
                #pragma unroll
                for (int n = 0; n < 4; ++n) {
                    int col = n0 + wc * 64 + n * 16 + lrow;
                    float vv = acc[m][n][j] + bias[e * OUT_C + col];
                    orow[col] = vv > 0.f ? vv : 0.f;
                }
            }
        }
    }
}

// ---------------- launch ----------------

extern "C" void kernel_launch(void* const* d_in, const int* in_sizes, int n_in,
                              void* d_out, int out_size, void* d_ws, size_t ws_size,
                              hipStream_t stream) {
    const float* x    = (const float*)d_in[0];
    const int*   idx  = (const int*)d_in[1];
    const float* w    = (const float*)d_in[2];
    const float* bias = (const float*)d_in[3];
    float* out = (float*)d_out;

    const size_t need = CTRL_OFF_BYTES + (size_t)(CTRL_INTS + 64) * sizeof(int);
    if (ws_size >= need) {
        unsigned short* xb = (unsigned short*)d_ws;
        int* ctrl = (int*)((char*)d_ws + CTRL_OFF_BYTES);

        prep_kernel<<<PREP_NWG, 256, 0, stream>>>(x, idx, xb, ctrl);
        gemm_kernel<<<MAX_TILES * 8, 256, 0, stream>>>(xb, w, bias, ctrl, out);
    } else {
        int* ctrl = (int*)d_ws;
        hipMemsetAsync(ctrl, 0, (CTRL_INTS + 64) * sizeof(int), stream);
        count_kernel<<<NTOK / 256, 256, 0, stream>>>(idx, ctrl);
        scan_kernel<<<1, 64, 0, stream>>>(ctrl);
        scatter_kernel<<<NTOK / 256, 256, 0, stream>>>(idx, ctrl);
        dim3 grid(MAX_TILES, OUT_C / BN);
        gemm_f32_kernel<<<grid, 256, 0, stream>>>(x, w, bias, ctrl, out);
    }
}